// Round 7
// baseline (346.514 us; speedup 1.0000x reference)
//
#include <hip/hip_runtime.h>

#define NN 50000
#define EE 800000
#define DD 128
#define RR 8
#define KSTACK 1152    // (RR+1)*DD stacked K
#define NR2 (NN * RR)  // 400000
#define RPB 16         // dst rows per fused block
#define ROWB 2304      // bytes per A-tile row (1152 bf16; XOR swizzle, no pad)
#define DUMP16 2304    // (RPB*ROWB)>>4 : dump slot base16 for dummy edges

typedef __attribute__((ext_vector_type(8))) short bf16x8;
typedef __attribute__((ext_vector_type(4))) float f32x4;

__device__ inline float bf2f(ushort u) {
    union { uint i; float f; } v; v.i = ((uint)u) << 16; return v.f;
}
__device__ inline ushort f2bf(float f) {
    uint b = __float_as_uint(f);
    uint r = (b + 0x7fffu + ((b >> 16) & 1u)) >> 16;
    return (ushort)r;
}

// Tiled weight build with LDS transpose: coalesced basis reads (o-major),
// coalesced 32B wT writes (k-major). Grid: (36 k-tiles, 2 layers).
__global__ void __launch_bounds__(256) k_build_w3(
        const float* __restrict__ b0, const float* __restrict__ c0,
        const float* __restrict__ r0, const float* __restrict__ b1,
        const float* __restrict__ c1, const float* __restrict__ r1,
        ushort* __restrict__ w0, ushort* __restrict__ w1) {
    __shared__ float tile[32][132];   // 16,896 B; pad 132 breaks column-read conflicts
    const float* basis = blockIdx.y ? b1 : b0;
    const float* comp  = blockIdx.y ? c1 : c0;
    const float* root  = blockIdx.y ? r1 : r0;
    ushort* wT         = blockIdx.y ? w1 : w0;
    int tid = threadIdx.x;
    int k0 = blockIdx.x * 32;
    #pragma unroll
    for (int it = 0; it < 16; ++it) {
        int idx = it * 256 + tid;
        int kk = idx >> 7, o = idx & 127;
        int k = k0 + kk;
        float val;
        if (k < RR * DD) {
            int r = k >> 7, i = k & 127;
            float s = 0.f;
            #pragma unroll
            for (int b = 0; b < 8; ++b) s += comp[r * 8 + b] * basis[(b * 128 + i) * 128 + o];
            val = s;
        } else {
            val = root[(k - RR * DD) * 128 + o];
        }
        tile[kk][o] = val;
    }
    __syncthreads();
    int o = tid >> 1, half = tid & 1;
    ushort* wp = wT + (size_t)o * KSTACK + k0 + half * 16;
    #pragma unroll
    for (int j = 0; j < 8; ++j) {
        float lo = tile[half * 16 + 2 * j][o];
        float hi = tile[half * 16 + 2 * j + 1][o];
        uint pk;
        asm("v_cvt_pk_bf16_f32 %0, %1, %2" : "=v"(pk) : "v"(lo), "v"(hi));
        *(uint*)(wp + 2 * j) = pk;
    }
}

__global__ void k_cvt_bf16(const float* __restrict__ x, ushort* __restrict__ xb, int n4) {
    int i = blockIdx.x * 256 + threadIdx.x;
    if (i < n4) {
        float4 v = ((const float4*)x)[i];
        uint2 p;
        p.x = (uint)f2bf(v.x) | ((uint)f2bf(v.y) << 16);
        p.y = (uint)f2bf(v.z) | ((uint)f2bf(v.w) << 16);
        ((uint2*)xb)[i] = p;
    }
}

__global__ void k_hist(const int* __restrict__ ei, const int* __restrict__ et,
                       int* __restrict__ deg_dr) {
    int e = blockIdx.x * 256 + threadIdx.x;
    if (e < EE) atomicAdd(&deg_dr[ei[EE + e] * RR + et[e]], 1);
}

__device__ inline int rowdeg(const int* __restrict__ deg_dr, int n) {
    int4 a = ((const int4*)deg_dr)[2 * n];
    int4 b = ((const int4*)deg_dr)[2 * n + 1];
    return a.x + a.y + a.z + a.w + b.x + b.y + b.z + b.w;
}

__global__ void k_scan1(const int* __restrict__ deg_dr, int* __restrict__ bsum, int n) {
    __shared__ int s[256];
    int t = threadIdx.x;
    int i = blockIdx.x * 256 + t;
    s[t] = (i < n) ? rowdeg(deg_dr, i) : 0;
    __syncthreads();
    for (int o = 128; o > 0; o >>= 1) {
        if (t < o) s[t] += s[t + o];
        __syncthreads();
    }
    if (t == 0) bsum[blockIdx.x] = s[0];
}

__global__ void k_scan2(int* __restrict__ bsum, int nb) {
    __shared__ int s[256];
    int t = threadIdx.x;
    int v = (t < nb) ? bsum[t] : 0;
    s[t] = v;
    __syncthreads();
    for (int o = 1; o < 256; o <<= 1) {
        int u = (t >= o) ? s[t - o] : 0;
        __syncthreads();
        s[t] += u;
        __syncthreads();
    }
    if (t < nb) bsum[t] = s[t] - v;   // exclusive
}

__global__ void k_scan3(const int* __restrict__ deg_dr, const int* __restrict__ boff,
                        int* __restrict__ ptr, int n) {
    __shared__ int s[256];
    int t = threadIdx.x;
    int i = blockIdx.x * 256 + t;
    int v = (i < n) ? rowdeg(deg_dr, i) : 0;
    s[t] = v;
    __syncthreads();
    for (int o = 1; o < 256; o <<= 1) {
        int u = (t >= o) ? s[t - o] : 0;
        __syncthreads();
        s[t] += u;
        __syncthreads();
    }
    if (i < n) ptr[i + 1] = boff[blockIdx.x] + s[t];
    if (i == 0) ptr[0] = 0;
}

// Per edge at (dst,rel)-sorted position:
//   ekw.x = (base16<<19) | ((lrow&7)<<16) | src,  base16 = (lrow*ROWB + rel*256)>>4
//   ekw.y = 1/deg(dst,rel)
__global__ void k_scatter(const int* __restrict__ ei, const int* __restrict__ et,
                          const int* __restrict__ row_ptr, const int* __restrict__ deg_dr,
                          int* __restrict__ cursor, int2* __restrict__ ekw) {
    int e = blockIdx.x * 256 + threadIdx.x;
    if (e < EE) {
        int s = ei[e], d = ei[EE + e], t = et[e];
        int4 a = ((const int4*)deg_dr)[2 * d];
        int4 b = ((const int4*)deg_dr)[2 * d + 1];
        int pre = 0;
        pre += (t > 0) ? a.x : 0; pre += (t > 1) ? a.y : 0;
        pre += (t > 2) ? a.z : 0; pre += (t > 3) ? a.w : 0;
        pre += (t > 4) ? b.x : 0; pre += (t > 5) ? b.y : 0;
        pre += (t > 6) ? b.z : 0;
        int deg = (t == 0) ? a.x : (t == 1) ? a.y : (t == 2) ? a.z : (t == 3) ? a.w
                : (t == 4) ? b.x : (t == 5) ? b.y : (t == 6) ? b.z : b.w;
        int p = row_ptr[d] + pre + atomicAdd(&cursor[d * RR + t], 1);
        int lrow = d & (RPB - 1);
        int base16 = lrow * (ROWB >> 4) + t * 16;
        int2 pk;
        pk.x = (base16 << 19) | ((lrow & 7) << 16) | s;
        pk.y = __float_as_int(1.f / (float)deg);
        ekw[p] = pk;
    }
}

// Fused layer. Block = 16 dst rows, 512 threads (8 waves), 37.1KB LDS ->
// 4 blocks/CU = 32 waves/CU (full occupancy; VGPR must stay <= 64).
// Phase 1: each wave owns 2 rows as ONE flat (dst,rel)-sorted edge stream;
//          2-deep software pipeline in chunks of 8; register run-accumulation,
//          unconditional overwrite-flush to bf16 A-tile (last write of a run
//          holds the full f32 sum). Tail edges = branch-free dummies (w=0).
// Phase 2: 36 K-step MFMA GEMM [16x1152]@[1152x128]; A from XOR-swizzled LDS,
//          B streamed from L2-resident wT; fused bias (+ReLU).
__global__ void __launch_bounds__(512, 8) k_fused5(
        const ushort* __restrict__ in, const int* __restrict__ rp,
        const int2* __restrict__ ekw, const ushort* __restrict__ BT,
        const float* __restrict__ bias, ushort* __restrict__ hout,
        float* __restrict__ fout) {
    __shared__ uint4 at4[(RPB * ROWB + 256) / 16];   // 37,120 B
    char* atb = (char*)at4;
    int tid = threadIdx.x, wid = tid >> 6, lane = tid & 63;
    int blockrow = blockIdx.x * RPB;
    uint lane4 = (uint)lane << 2;

    {
        uint4 z = {0u, 0u, 0u, 0u};
        for (int i = tid; i < (RPB * ROWB + 256) / 16; i += 512) at4[i] = z;
    }
    __syncthreads();

    const ushort* inl = in + (lane << 1);

    // self (root) slots, coalesced reads
    #pragma unroll
    for (int rr = 0; rr < 2; ++rr) {
        int lr = (wid << 1) + rr;
        int n = blockrow + lr;
        if (n < NN) {
            uint su = *(const uint*)(inl + (size_t)n * DD);
            uint off = (uint)(lr * ROWB + 2048) + (lane4 ^ ((uint)(lr & 7) << 4));
            *(uint*)(atb + off) = su;
        }
    }

    // flat edge range for this wave's 2 rows
    int n0 = blockrow + (wid << 1);
    int i0 = n0 < NN ? n0 : NN;
    int i1 = n0 + 2 < NN ? n0 + 2 : NN;
    int p    = __builtin_amdgcn_readfirstlane(rp[i0]);
    int pend = __builtin_amdgcn_readfirstlane(rp[i1]);
    int nb = pend - p;

    const int U = 8;
    int2 kA[U], kB[U];
    uint gA[U], gB[U];
    float a0 = 0.f, a1 = 0.f;
    uint prev = 0xFFFFFFFFu;

    auto loadc = [&](int2* kb, uint* gb, int base) {
        #pragma unroll
        for (int j = 0; j < U; ++j) {
            int pe = base + j;
            bool dummy = pe >= pend;
            pe = dummy ? (pend - 1) : pe;
            int2 e = ekw[pe];
            if (dummy) { e.x = (int)((uint)DUMP16 << 19); e.y = 0; }
            kb[j] = e;
        }
        #pragma unroll
        for (int j = 0; j < U; ++j)
            gb[j] = *(const uint*)(inl + ((size_t)(kb[j].x & 0xFFFF)) * DD);
    };
    auto proc = [&](int2* kb, uint* gb) {
        #pragma unroll
        for (int j = 0; j < U; ++j) {
            uint ex = (uint)kb[j].x;
            float w = __int_as_float(kb[j].y);
            uint off = ((ex >> 19) << 4) + (lane4 ^ ((ex >> 12) & 0x70u));
            bool same = (off == prev);
            a0 = same ? a0 : 0.f;
            a1 = same ? a1 : 0.f;
            uint g = gb[j];
            a0 += w * bf2f((ushort)(g & 0xFFFFu));
            a1 += w * bf2f((ushort)(g >> 16));
            uint pk;
            asm("v_cvt_pk_bf16_f32 %0, %1, %2" : "=v"(pk) : "v"(a0), "v"(a1));
            *(uint*)(atb + off) = pk;
            prev = off;
        }
    };

    if (nb > 0) {
        int nch = (nb + U - 1) / U;
        loadc(kA, gA, p);
        int i = 1;
        for (; i + 1 < nch; i += 2) {
            loadc(kB, gB, p + i * U);
            proc(kA, gA);
            loadc(kA, gA, p + (i + 1) * U);
            proc(kB, gB);
        }
        if (i < nch) {
            loadc(kB, gB, p + i * U);
            proc(kA, gA);
            proc(kB, gB);
        } else {
            proc(kA, gA);
        }
    }
    __syncthreads();

    // Phase 2: wave wid -> cols [wid*16, wid*16+16), rows 0..15 (1 fragment).
    int rlo = lane & 15, q = lane >> 4;
    int colbase = wid << 4;
    uint x7 = (uint)(rlo & 7) << 4;
    const char* arow = atb + rlo * ROWB;
    const ushort* bp = BT + (size_t)(colbase + rlo) * KSTACK + (q << 3);
    f32x4 c0 = {0.f, 0.f, 0.f, 0.f};
    #pragma unroll 4
    for (int kk = 0; kk < KSTACK / 32; ++kk) {
        uint loff = (uint)(kk * 64 + q * 16) ^ x7;
        bf16x8 b  = *(const bf16x8*)(bp + kk * 32);
        bf16x8 af = *(const bf16x8*)(arow + loff);
        c0 = __builtin_amdgcn_mfma_f32_16x16x32_bf16(af, b, c0, 0, 0, 0);
    }
    int col = colbase + rlo;
    float bv = bias[col];
    int rowoff = q << 2;
    #pragma unroll
    for (int rg = 0; rg < 4; ++rg) {
        int row = blockrow + rowoff + rg;
        if (row < NN) {
            float v = c0[rg] + bv;
            if (hout) {
                v = fmaxf(v, 0.f);
                hout[(size_t)row * DD + col] = f2bf(v);
            } else {
                fout[(size_t)row * DD + col] = v;
            }
        }
    }
}

extern "C" void kernel_launch(void* const* d_in, const int* in_sizes, int n_in,
                              void* d_out, int out_size, void* d_ws, size_t ws_size,
                              hipStream_t stream) {
    const float* x      = (const float*)d_in[0];
    const int*   ei     = (const int*)d_in[1];
    const int*   et     = (const int*)d_in[2];
    const float* basis0 = (const float*)d_in[3];
    const float* comp0  = (const float*)d_in[4];
    const float* root0  = (const float*)d_in[5];
    const float* bias0  = (const float*)d_in[6];
    const float* basis1 = (const float*)d_in[7];
    const float* comp1  = (const float*)d_in[8];
    const float* root1  = (const float*)d_in[9];
    const float* bias1  = (const float*)d_in[10];
    float* out = (float*)d_out;

    char* ws = (char*)d_ws;
    size_t off = 0;
    auto alloc = [&](size_t bytes) -> void* {
        void* p = ws + off;
        off += (bytes + 255) & ~(size_t)255;
        return p;
    };
    int*    deg_dr  = (int*)alloc((size_t)NR2 * 4);
    int*    cursor  = (int*)alloc((size_t)NR2 * 4);
    size_t zero_bytes = off;
    int*    row_ptr = (int*)alloc((size_t)(NN + 1) * 4);
    int*    bsum    = (int*)alloc(256 * 4);
    int2*   ekw     = (int2*)alloc((size_t)EE * 8);
    ushort* wT0     = (ushort*)alloc((size_t)DD * KSTACK * 2);
    ushort* wT1     = (ushort*)alloc((size_t)DD * KSTACK * 2);
    ushort* xb      = (ushort*)alloc((size_t)NN * DD * 2);
    ushort* h       = (ushort*)alloc((size_t)NN * DD * 2);
    if (off > ws_size) return;

    hipMemsetAsync(d_ws, 0, zero_bytes, stream);

    dim3 wgrid(KSTACK / 32, 2);   // 36 x 2
    k_build_w3<<<wgrid, 256, 0, stream>>>(basis0, comp0, root0, basis1, comp1, root1, wT0, wT1);
    k_cvt_bf16<<<6250, 256, 0, stream>>>(x, xb, NN * DD / 4);
    k_hist<<<3125, 256, 0, stream>>>(ei, et, deg_dr);
    k_scan1<<<196, 256, 0, stream>>>(deg_dr, bsum, NN);
    k_scan2<<<1, 256, 0, stream>>>(bsum, 196);
    k_scan3<<<196, 256, 0, stream>>>(deg_dr, bsum, row_ptr, NN);
    k_scatter<<<3125, 256, 0, stream>>>(ei, et, row_ptr, deg_dr, cursor, ekw);

    int fblocks = NN / RPB;   // 3125, exact
    k_fused5<<<fblocks, 512, 0, stream>>>(xb, row_ptr, ekw, wT0, bias0, h, nullptr);
    k_fused5<<<fblocks, 512, 0, stream>>>(h, row_ptr, ekw, wT1, bias1, nullptr, out);
}

// Round 8
// 325.898 us; speedup vs baseline: 1.0633x; 1.0633x over previous
//
#include <hip/hip_runtime.h>

#define NN 50000
#define EE 800000
#define DD 128
#define RR 8
#define KSTACK 1152    // (RR+1)*DD stacked K
#define NR2 (NN * RR)  // 400000
#define RPB 32         // dst rows per fused block
#define ROWB 2304      // bytes per A-tile row (1152 bf16; XOR swizzle, no pad)
#define DUMPB 73728u   // RPB*ROWB: dump slot byte base for dummy edges

typedef __attribute__((ext_vector_type(8))) short bf16x8;
typedef __attribute__((ext_vector_type(4))) float f32x4;

__device__ inline float bf2f(ushort u) {
    union { uint i; float f; } v; v.i = ((uint)u) << 16; return v.f;
}
__device__ inline ushort f2bf(float f) {
    uint b = __float_as_uint(f);
    uint r = (b + 0x7fffu + ((b >> 16) & 1u)) >> 16;
    return (ushort)r;
}

// Tiled weight build with LDS transpose: coalesced basis reads (o-major),
// coalesced 32B wT writes (k-major). Grid: (36 k-tiles, 2 layers).
__global__ void __launch_bounds__(256) k_build_w3(
        const float* __restrict__ b0, const float* __restrict__ c0,
        const float* __restrict__ r0, const float* __restrict__ b1,
        const float* __restrict__ c1, const float* __restrict__ r1,
        ushort* __restrict__ w0, ushort* __restrict__ w1) {
    __shared__ float tile[32][132];
    const float* basis = blockIdx.y ? b1 : b0;
    const float* comp  = blockIdx.y ? c1 : c0;
    const float* root  = blockIdx.y ? r1 : r0;
    ushort* wT         = blockIdx.y ? w1 : w0;
    int tid = threadIdx.x;
    int k0 = blockIdx.x * 32;
    #pragma unroll
    for (int it = 0; it < 16; ++it) {
        int idx = it * 256 + tid;
        int kk = idx >> 7, o = idx & 127;
        int k = k0 + kk;
        float val;
        if (k < RR * DD) {
            int r = k >> 7, i = k & 127;
            float s = 0.f;
            #pragma unroll
            for (int b = 0; b < 8; ++b) s += comp[r * 8 + b] * basis[(b * 128 + i) * 128 + o];
            val = s;
        } else {
            val = root[(k - RR * DD) * 128 + o];
        }
        tile[kk][o] = val;
    }
    __syncthreads();
    int o = tid >> 1, half = tid & 1;
    ushort* wp = wT + (size_t)o * KSTACK + k0 + half * 16;
    #pragma unroll
    for (int j = 0; j < 8; ++j) {
        float lo = tile[half * 16 + 2 * j][o];
        float hi = tile[half * 16 + 2 * j + 1][o];
        uint pk;
        asm("v_cvt_pk_bf16_f32 %0, %1, %2" : "=v"(pk) : "v"(lo), "v"(hi));
        *(uint*)(wp + 2 * j) = pk;
    }
}

__global__ void k_cvt_bf16(const float* __restrict__ x, ushort* __restrict__ xb, int n4) {
    int i = blockIdx.x * 256 + threadIdx.x;
    if (i < n4) {
        float4 v = ((const float4*)x)[i];
        uint2 p;
        p.x = (uint)f2bf(v.x) | ((uint)f2bf(v.y) << 16);
        p.y = (uint)f2bf(v.z) | ((uint)f2bf(v.w) << 16);
        ((uint2*)xb)[i] = p;
    }
}

__global__ void k_hist(const int* __restrict__ ei, const int* __restrict__ et,
                       int* __restrict__ deg_dr) {
    int e = blockIdx.x * 256 + threadIdx.x;
    if (e < EE) atomicAdd(&deg_dr[ei[EE + e] * RR + et[e]], 1);
}

__device__ inline int rowdeg(const int* __restrict__ deg_dr, int n) {
    int4 a = ((const int4*)deg_dr)[2 * n];
    int4 b = ((const int4*)deg_dr)[2 * n + 1];
    return a.x + a.y + a.z + a.w + b.x + b.y + b.z + b.w;
}

__global__ void k_scan1(const int* __restrict__ deg_dr, int* __restrict__ bsum, int n) {
    __shared__ int s[256];
    int t = threadIdx.x;
    int i = blockIdx.x * 256 + t;
    s[t] = (i < n) ? rowdeg(deg_dr, i) : 0;
    __syncthreads();
    for (int o = 128; o > 0; o >>= 1) {
        if (t < o) s[t] += s[t + o];
        __syncthreads();
    }
    if (t == 0) bsum[blockIdx.x] = s[0];
}

__global__ void k_scan2(int* __restrict__ bsum, int nb) {
    __shared__ int s[256];
    int t = threadIdx.x;
    int v = (t < nb) ? bsum[t] : 0;
    s[t] = v;
    __syncthreads();
    for (int o = 1; o < 256; o <<= 1) {
        int u = (t >= o) ? s[t - o] : 0;
        __syncthreads();
        s[t] += u;
        __syncthreads();
    }
    if (t < nb) bsum[t] = s[t] - v;   // exclusive
}

__global__ void k_scan3(const int* __restrict__ deg_dr, const int* __restrict__ boff,
                        int* __restrict__ ptr, int n) {
    __shared__ int s[256];
    int t = threadIdx.x;
    int i = blockIdx.x * 256 + t;
    int v = (i < n) ? rowdeg(deg_dr, i) : 0;
    s[t] = v;
    __syncthreads();
    for (int o = 1; o < 256; o <<= 1) {
        int u = (t >= o) ? s[t - o] : 0;
        __syncthreads();
        s[t] += u;
        __syncthreads();
    }
    if (i < n) ptr[i + 1] = boff[blockIdx.x] + s[t];
    if (i == 0) ptr[0] = 0;
}

// Per edge at (dst,rel)-sorted position:
//   ekw.x = (base16<<19) | ((lrow&7)<<16) | src,  base16 = (lrow*ROWB + rel*256)>>4
//   ekw.y = 1/deg(dst,rel)
__global__ void k_scatter(const int* __restrict__ ei, const int* __restrict__ et,
                          const int* __restrict__ row_ptr, const int* __restrict__ deg_dr,
                          int* __restrict__ cursor, int2* __restrict__ ekw) {
    int e = blockIdx.x * 256 + threadIdx.x;
    if (e < EE) {
        int s = ei[e], d = ei[EE + e], t = et[e];
        int4 a = ((const int4*)deg_dr)[2 * d];
        int4 b = ((const int4*)deg_dr)[2 * d + 1];
        int pre = 0;
        pre += (t > 0) ? a.x : 0; pre += (t > 1) ? a.y : 0;
        pre += (t > 2) ? a.z : 0; pre += (t > 3) ? a.w : 0;
        pre += (t > 4) ? b.x : 0; pre += (t > 5) ? b.y : 0;
        pre += (t > 6) ? b.z : 0;
        int deg = (t == 0) ? a.x : (t == 1) ? a.y : (t == 2) ? a.z : (t == 3) ? a.w
                : (t == 4) ? b.x : (t == 5) ? b.y : (t == 6) ? b.z : b.w;
        int p = row_ptr[d] + pre + atomicAdd(&cursor[d * RR + t], 1);
        int lrow = d & (RPB - 1);
        int base16 = lrow * (ROWB >> 4) + t * 16;
        int2 pk;
        pk.x = (base16 << 19) | ((lrow & 7) << 16) | s;
        pk.y = __float_as_int(1.f / (float)deg);
        ekw[p] = pk;
    }
}

// Fused layer. Block = 32 dst rows, 512 threads (8 waves), 74KB LDS -> 2 blocks/CU.
// Phase 1: wave owns 4 rows as one flat (dst,rel)-sorted edge stream.
//   - Keys preloaded 64-at-a-time with ONE coalesced load (lane i holds edge i's key);
//     extracted via readlane -> SGPR (scalar gather base, key load off critical path).
//   - 16-deep gather pipeline (g0/g1 double buffer, fully unrolled).
//   - Register run-accumulation; unconditional overwrite-flush to bf16 A-tile
//     (last write of a (row,rel)-run holds the full f32 sum). Dummies -> dump, w=0.
// Phase 2: 36 K-step MFMA GEMM [32x1152]@[1152x128]; A from XOR-swizzled LDS,
//   B streamed from L2-resident wT; fused bias (+ReLU).
__global__ void __launch_bounds__(512, 4) k_fused6(
        const ushort* __restrict__ in, const int* __restrict__ rp,
        const int2* __restrict__ ekw, const ushort* __restrict__ BT,
        const float* __restrict__ bias, ushort* __restrict__ hout,
        float* __restrict__ fout) {
    __shared__ uint4 at4[(RPB * ROWB + 256) / 16];   // 73,984 B
    char* atb = (char*)at4;
    int tid = threadIdx.x, wid = tid >> 6, lane = tid & 63;
    int blockrow = blockIdx.x * RPB;
    uint lane4 = (uint)lane << 2;

    {
        uint4 z = {0u, 0u, 0u, 0u};
        for (int i = tid; i < (RPB * ROWB + 256) / 16; i += 512) at4[i] = z;
    }
    __syncthreads();

    const ushort* inl = in + (lane << 1);

    // self (root) slots, coalesced reads
    #pragma unroll
    for (int rr = 0; rr < 4; ++rr) {
        int lr = (wid << 2) + rr;
        int n = blockrow + lr;
        if (n < NN) {
            uint su = *(const uint*)(inl + (size_t)n * DD);
            uint off = (uint)(lr * ROWB + 2048) + (lane4 ^ ((uint)(lr & 7) << 4));
            *(uint*)(atb + off) = su;
        }
    }

    int n0 = blockrow + (wid << 2);
    int i0 = n0 < NN ? n0 : NN;
    int i1 = n0 + 4 < NN ? n0 + 4 : NN;
    int p    = __builtin_amdgcn_readfirstlane(rp[i0]);
    int pend = __builtin_amdgcn_readfirstlane(rp[i1]);
    int nb   = pend - p;

    if (nb > 0) {
        float a0 = 0.f, a1 = 0.f;
        uint prevsid = 0xFFFFFFFFu;
        uint g0[16], g1[16];
        int kvx, kvy, nkvx = 0, nkvy = 0;
        {
            int li = lane < nb ? lane : nb - 1;
            int2 e = ekw[p + li];
            kvx = e.x; kvy = e.y;
        }
        int nbatch = (nb + 63) >> 6;

#define ISSUE(G, CB) \
        _Pragma("unroll") \
        for (int j = 0; j < 16; ++j) { \
            uint sx = (uint)__builtin_amdgcn_readlane(kvx, (CB) + j); \
            const ushort* src = in + (size_t)(sx & 0xFFFFu) * DD; \
            G[j] = *(const uint*)(src + (lane << 1)); \
        }
#define PROC(G, CB) \
        _Pragma("unroll") \
        for (int j = 0; j < 16; ++j) { \
            uint sx = (uint)__builtin_amdgcn_readlane(kvx, (CB) + j); \
            int  sy = __builtin_amdgcn_readlane(kvy, (CB) + j); \
            bool real = ((CB) + j) < rem; \
            float w = real ? __int_as_float(sy) : 0.f; \
            uint sid = real ? (sx >> 16) : 0xFFFFFFFFu; \
            uint offu = real ? ((sx >> 19) << 4) : DUMPB; \
            uint offv = offu + (lane4 ^ ((sx >> 12) & 0x70u)); \
            bool same = (sid == prevsid); \
            a0 = same ? a0 : 0.f; \
            a1 = same ? a1 : 0.f; \
            uint g = G[j]; \
            a0 += w * bf2f((ushort)(g & 0xFFFFu)); \
            a1 += w * bf2f((ushort)(g >> 16)); \
            uint pk; \
            asm("v_cvt_pk_bf16_f32 %0, %1, %2" : "=v"(pk) : "v"(a0), "v"(a1)); \
            *(uint*)(atb + offv) = pk; \
            prevsid = sid; \
        }

        for (int b = 0; b < nbatch; ++b) {
            int base = p + (b << 6);
            int rem = pend - base;       // uniform, > 0
            if (b + 1 < nbatch) {        // prefetch next batch's keys (hidden ~4 chunks)
                int nbase = base + 64;
                int nrem = pend - nbase;
                int li = lane < nrem ? lane : nrem - 1;
                int2 e = ekw[nbase + li];
                nkvx = e.x; nkvy = e.y;
            }
            ISSUE(g0, 0)
            ISSUE(g1, 16) PROC(g0, 0)
            ISSUE(g0, 32) PROC(g1, 16)
            ISSUE(g1, 48) PROC(g0, 32)
            PROC(g1, 48)
            kvx = nkvx; kvy = nkvy;
        }
#undef ISSUE
#undef PROC
    }
    __syncthreads();

    // Phase 2: wave wid -> cols [wid*16, wid*16+16), rows 0..31 (2 fragments).
    int rlo = lane & 15, q = lane >> 4;
    int colbase = wid << 4;
    uint x7 = (uint)(rlo & 7) << 4;
    const char* arow0 = atb + rlo * ROWB;
    const char* arow1 = atb + (rlo + 16) * ROWB;
    const ushort* bp = BT + (size_t)(colbase + rlo) * KSTACK + (q << 3);
    f32x4 c0 = {0.f, 0.f, 0.f, 0.f}, c1 = {0.f, 0.f, 0.f, 0.f};
    #pragma unroll 4
    for (int kk = 0; kk < KSTACK / 32; ++kk) {
        uint loff = (uint)(kk * 64 + q * 16) ^ x7;
        bf16x8 b   = *(const bf16x8*)(bp + kk * 32);
        bf16x8 a0f = *(const bf16x8*)(arow0 + loff);
        bf16x8 a1f = *(const bf16x8*)(arow1 + loff);
        c0 = __builtin_amdgcn_mfma_f32_16x16x32_bf16(a0f, b, c0, 0, 0, 0);
        c1 = __builtin_amdgcn_mfma_f32_16x16x32_bf16(a1f, b, c1, 0, 0, 0);
    }
    int col = colbase + rlo;
    float bv = bias[col];
    int rowoff = q << 2;
    #pragma unroll
    for (int f = 0; f < 2; ++f) {
        f32x4 cv = f ? c1 : c0;
        #pragma unroll
        for (int rg = 0; rg < 4; ++rg) {
            int row = blockrow + f * 16 + rowoff + rg;
            if (row < NN) {
                float v = cv[rg] + bv;
                if (hout) {
                    v = fmaxf(v, 0.f);
                    hout[(size_t)row * DD + col] = f2bf(v);
                } else {
                    fout[(size_t)row * DD + col] = v;
                }
            }
        }
    }
}

extern "C" void kernel_launch(void* const* d_in, const int* in_sizes, int n_in,
                              void* d_out, int out_size, void* d_ws, size_t ws_size,
                              hipStream_t stream) {
    const float* x      = (const float*)d_in[0];
    const int*   ei     = (const int*)d_in[1];
    const int*   et     = (const int*)d_in[2];
    const float* basis0 = (const float*)d_in[3];
    const float* comp0  = (const float*)d_in[4];
    const float* root0  = (const float*)d_in[5];
    const float* bias0  = (const float*)d_in[6];
    const float* basis1 = (const float*)d_in[7];
    const float* comp1  = (const float*)d_in[8];
    const float* root1  = (const float*)d_in[9];
    const float* bias1  = (const float*)d_in[10];
    float* out = (float*)d_out;

    char* ws = (char*)d_ws;
    size_t off = 0;
    auto alloc = [&](size_t bytes) -> void* {
        void* p = ws + off;
        off += (bytes + 255) & ~(size_t)255;
        return p;
    };
    int*    deg_dr  = (int*)alloc((size_t)NR2 * 4);
    int*    cursor  = (int*)alloc((size_t)NR2 * 4);
    size_t zero_bytes = off;
    int*    row_ptr = (int*)alloc((size_t)(NN + 1) * 4);
    int*    bsum    = (int*)alloc(256 * 4);
    int2*   ekw     = (int2*)alloc((size_t)EE * 8);
    ushort* wT0     = (ushort*)alloc((size_t)DD * KSTACK * 2);
    ushort* wT1     = (ushort*)alloc((size_t)DD * KSTACK * 2);
    ushort* xb      = (ushort*)alloc((size_t)NN * DD * 2);
    ushort* h       = (ushort*)alloc((size_t)NN * DD * 2);
    if (off > ws_size) return;

    hipMemsetAsync(d_ws, 0, zero_bytes, stream);

    dim3 wgrid(KSTACK / 32, 2);   // 36 x 2
    k_build_w3<<<wgrid, 256, 0, stream>>>(basis0, comp0, root0, basis1, comp1, root1, wT0, wT1);
    k_cvt_bf16<<<6250, 256, 0, stream>>>(x, xb, NN * DD / 4);
    k_hist<<<3125, 256, 0, stream>>>(ei, et, deg_dr);
    k_scan1<<<196, 256, 0, stream>>>(deg_dr, bsum, NN);
    k_scan2<<<1, 256, 0, stream>>>(bsum, 196);
    k_scan3<<<196, 256, 0, stream>>>(deg_dr, bsum, row_ptr, NN);
    k_scatter<<<3125, 256, 0, stream>>>(ei, et, row_ptr, deg_dr, cursor, ekw);

    int fblocks = (NN + RPB - 1) / RPB;   // 1563
    k_fused6<<<fblocks, 512, 0, stream>>>(xb, row_ptr, ekw, wT0, bias0, h, nullptr);
    k_fused6<<<fblocks, 512, 0, stream>>>(h, row_ptr, ekw, wT1, bias1, nullptr, out);
}